// Round 4
// baseline (255.966 us; speedup 1.0000x reference)
//
#include <hip/hip_runtime.h>
#include <math.h>

// CTC forward loss, linear-domain alpha recursion with power-of-2 renorm.
// B=256 -> one wave per batch, one block per CU. Lane l owns states 4l..4l+3
// (+ state 256 as slot 4 on lane 63).
//
// Round-4 change vs round-3: delete row staging + ds_bpermute entirely.
// Each lane needs only 3 scalars per row: p[t][ylab0], p[t][ylab1], p[t][127].
// Issue 3 direct global_load_dword per step, prefetched D=16 rows ahead
// (48 outstanding vmcnt entries, ~16-step slack). No DS ops in the hot loop.
// Arithmetic is bit-identical to round-3 (same (p+eps)*128 commits, same
// alpha update, same DPP renorm) -> output bit-identical.

#define T_DIM 1024
#define C_DIM 128
#define U_DIM 128
#define EPSF  1e-7f
#define LN2F  0.6931471805599453f
#define PSCALE 128.0f          // 2^7 per-step pre-scale (exact)
#define PSCALE_LOG2 7
#define TARGET_BEXP 286        // recenter wave-max at 2^32
#define PD 16                  // prob prefetch depth (rows ahead)

__device__ __forceinline__ float dpp_wave_shr1(float x) {
  // wave_shr:1 = 0x138; old=0 + bound_ctrl=false -> lane 0 reads exact 0.0f
  return __int_as_float(__builtin_amdgcn_update_dpp(
      0, __float_as_int(x), 0x138, 0xf, 0xf, false));
}
#define ROR_MAX(red, CTRL)                                                   \
  (red) = fmaxf((red), __int_as_float(__builtin_amdgcn_update_dpp(           \
      __float_as_int(red), __float_as_int(red), (CTRL), 0xf, 0xf, false)))

__global__ __launch_bounds__(64) void ctc_alpha_kernel(
    const int*   __restrict__ y_true,   // (B, U) int32
    const float* __restrict__ y_pred,   // (B, T, C) f32 softmax probs
    float*       __restrict__ out,      // (B, 1) f32
    int B)
{
  const int b = blockIdx.x;
  if (b >= B) return;
  const int lane = threadIdx.x;           // 0..63
  const float* __restrict__ p  = y_pred + (size_t)b * (T_DIM * C_DIM);
  const int*   __restrict__ yb = y_true + b * U_DIM;
  const int blank = C_DIM - 1;

  // Labels for this lane's odd states: s=4l+1 -> u=2l ; s=4l+3 -> u=2l+1
  const int ylab0 = yb[2 * lane];
  const int ylab1 = yb[2 * lane + 1];
  int yprev = blank;
  if (lane > 0) yprev = yb[2 * lane - 1];
  const float allow1 = (lane > 0 && ylab0 != blank && ylab0 != yprev) ? 1.0f : 0.0f;
  const float allow3 = (ylab1 != blank && ylab1 != ylab0)             ? 1.0f : 0.0f;

  // Blank index laundered into a VGPR so the compiler cannot scalarize the
  // blank load into SMEM (SMEM completes out-of-order on lgkmcnt).
  int blank_v;
  asm volatile("v_mov_b32 %0, 127" : "=v"(blank_v));

  // Per-row probability prefetch queues, PD rows deep (3 loads/row).
  float cbq[PD], c1q[PD], c3q[PD];
#pragma unroll
  for (int i = 0; i < PD; ++i) {
    const float* rp = p + (size_t)i * C_DIM;
    c1q[i] = rp[ylab0];
    c3q[i] = rp[ylab1];
    cbq[i] = rp[blank_v];
  }

  // Virtual init: alpha_{-1}=1 on lane0 makes t=0 a uniform step.
  float a0 = (lane == 0) ? 1.0f : 0.0f;
  float a1 = 0.f, a2 = 0.f, a3 = 0.f, a4 = 0.f;
  float red = 0.f;     // pipelined renorm reduction carrier
  int   rmb = 0;       // wave-max bits (uniform) from phase 5
  int   e_acc = 0;     // accumulated base-2 exponent removed by renorms

  for (int tb = 0; tb < T_DIM; tb += PD) {
#pragma unroll
    for (int u = 0; u < PD; ++u) {
      const int t = tb + u;

      // Commit row t's probabilities (bit-identical: (p+eps)*2^7).
      const float cb = (cbq[u] + EPSF) * PSCALE;
      const float c1 = (c1q[u] + EPSF) * PSCALE;
      const float c3 = (c3q[u] + EPSF) * PSCALE;

      // Refill slot u with row t+PD (clamped; tail values never committed).
      {
        int tn = t + PD; if (tn > T_DIM - 1) tn = T_DIM - 1;
        const float* rp = p + (size_t)tn * C_DIM;
        c1q[u] = rp[ylab0];
        c3q[u] = rp[ylab1];
        cbq[u] = rp[blank_v];
      }

      // Alpha update. sh3 via DPP wave_shr:1 (lane0 -> exact 0).
      float sh3 = dpp_wave_shr1(a3);
      float n0 = (a0 + sh3)                 * cb;
      float n1 = fmaf(sh3, allow1, a0 + a1) * c1;
      float n2 = (a1 + a2)                  * cb;
      float n3 = fmaf(a1,  allow3, a2 + a3) * c3;
      float n4 = (a3 + a4)                  * cb;   // state 256 (lane63)
      a0 = n0; a1 = n1; a2 = n2; a3 = n3; a4 = n4;

      // Renorm pipeline, period 8 (DPP row_ror + readlane + int max).
      const int ph = u & 7;
      if (ph == 0) {
        red = fmaxf(fmaxf(fmaxf(a0, a1), fmaxf(a2, a3)), a4);
      } else if (ph == 1) { ROR_MAX(red, 0x128);   // row_ror:8
      } else if (ph == 2) { ROR_MAX(red, 0x124);   // row_ror:4
      } else if (ph == 3) { ROR_MAX(red, 0x122);   // row_ror:2
      } else if (ph == 4) { ROR_MAX(red, 0x121);   // row_ror:1 -> row(16) max
      } else if (ph == 5) {
        // Cross-row: 4 readlanes + int max (positive floats order as ints).
        int r0 = __builtin_amdgcn_readlane(__float_as_int(red), 0);
        int r1 = __builtin_amdgcn_readlane(__float_as_int(red), 16);
        int r2 = __builtin_amdgcn_readlane(__float_as_int(red), 32);
        int r3 = __builtin_amdgcn_readlane(__float_as_int(red), 48);
        int m01 = r0 > r1 ? r0 : r1;
        int m23 = r2 > r3 ? r2 : r3;
        rmb = m01 > m23 ? m01 : m23;
      } else if (ph == 7) {
        int eb = (rmb >> 23) & 0xff;                      // biased exp of wave max
        int sb = TARGET_BEXP - eb;                        // recenter max at 2^32
        if (sb > 254) sb = 254;
        float sc = __uint_as_float((unsigned)sb << 23);   // exact power of 2
        a0 *= sc; a1 *= sc; a2 *= sc; a3 *= sc; a4 *= sc;
        e_acc += 127 - sb;
      }
    }
  }

  if (lane == 63) {
    float s = a3 + a4;                 // alpha[255] + alpha[256]
    s = fmaxf(s, 1e-37f);
    // true log = log(stored) + e_acc*ln2 - (T*7)*ln2  (undo per-step 2^7)
    float ll = logf(s) + (float)(e_acc - T_DIM * PSCALE_LOG2) * LN2F;
    out[b] = -ll;
  }
}

extern "C" void kernel_launch(void* const* d_in, const int* in_sizes, int n_in,
                              void* d_out, int out_size, void* d_ws, size_t ws_size,
                              hipStream_t stream) {
  const int*   y_true = (const int*)d_in[0];
  const float* y_pred = (const float*)d_in[1];
  float*       out    = (float*)d_out;
  const int B = in_sizes[0] / U_DIM;   // 256
  ctc_alpha_kernel<<<dim3(B), dim3(64), 0, stream>>>(y_true, y_pred, out, B);
}

// Round 7
// 202.356 us; speedup vs baseline: 1.2649x; 1.2649x over previous
//
#include <hip/hip_runtime.h>
#include <math.h>

// CTC forward loss, linear-domain alpha recursion, power-of-2 renorm.
// B=256 -> one wave per batch/CU. Lane l owns states 4l..4l+3 (+ state 256
// as slot 4 on lane 63).
//
// Round-7: the ENTIRE hot loop is ONE asm volatile block with hard-coded,
// clobber-declared registers. R5/R6 faulted because "+v"-tied waitcnt asm
// pins values, not registers: the allocator's live-range-split copies read
// in-flight load destinations early and freed them for reuse -> landing
// loads clobbered reallocated regs (store address) -> wild store -> fault.
// Inside one blob the allocator cannot touch v20-v79, so the 48-deep VMEM
// queue (16 rows x {c1,c3,cb}) with s_waitcnt vmcnt(45) is deterministic.
// Epilogue drains vmcnt to 0 before any register leaves the blob.
//
// Numerics: commit = p + EPS (no per-step prescale); every 8th step an
// exact power-of-2 renorm recenters the wave max at 2^40 (sb = 294 - eb,
// clamped <= 254), e_acc accumulates 127-sb. ll = log(s) + e_acc*ln2.

#define T_DIM 1024
#define C_DIM 128
#define U_DIM 128
#define LN2F  0.6931471805599453f

// ---- asm text macros ------------------------------------------------------
// v20 = voff(label0), v21 = voff(label1), v22 = row base (blank via offset:508)
// v23-v25 temps, v26=cb, v27=c1, v28=c3, v29 = renorm max, v30=allow1, v31=allow3
// queue: row u: c1=v(32+u), c3=v(48+u), cb=v(64+u)
// s90 loop counter, s91-s95 renorm scratch.

#define EPS_LIT "0x33d6bf95"   /* 1e-7f */

#define ROWLOAD(Q1,Q3,QB) \
  "global_load_dword " Q1 ", v20, %[P]\n\t" \
  "global_load_dword " Q3 ", v21, %[P]\n\t" \
  "global_load_dword " QB ", v22, %[P] offset:508\n\t" \
  "v_add_u32 v20, 0x200, v20\n\t" \
  "v_add_u32 v21, 0x200, v21\n\t" \
  "v_add_u32 v22, 0x200, v22\n\t"

#define COMMIT(Q1,Q3,QB) \
  "v_add_f32 v27, " EPS_LIT ", " Q1 "\n\t" \
  "v_add_f32 v28, " EPS_LIT ", " Q3 "\n\t" \
  "v_add_f32 v26, " EPS_LIT ", " QB "\n\t"

// 13 VALU ops; old-alpha reads all precede their overwrites.
#define ALPHA \
  "v_mov_b32_dpp v23, %[A3] wave_shr:1 row_mask:0xf bank_mask:0xf bound_ctrl:0\n\t" \
  "v_add_f32 v24, %[A0], v23\n\t" \
  "v_add_f32 v25, %[A0], %[A1]\n\t" \
  "v_fma_f32 v25, v23, v30, v25\n\t" \
  "v_mul_f32 %[A0], v24, v26\n\t" \
  "v_add_f32 v24, %[A1], %[A2]\n\t" \
  "v_add_f32 v23, %[A2], %[A3]\n\t" \
  "v_fma_f32 v23, %[A1], v31, v23\n\t" \
  "v_mul_f32 %[A1], v25, v27\n\t" \
  "v_mul_f32 %[A2], v24, v26\n\t" \
  "v_add_f32 v24, %[A3], %[A4]\n\t" \
  "v_mul_f32 %[A3], v23, v28\n\t" \
  "v_mul_f32 %[A4], v24, v26\n\t"

// Exact power-of-2 renorm: wave max -> recenter at 2^40. s_nop pads DPP /
// readlane hazards. Positive floats compare correctly as unsigned ints.
#define RENORM \
  "v_max_f32 v29, %[A0], %[A1]\n\t" \
  "v_max_f32 v29, v29, %[A2]\n\t" \
  "v_max_f32 v29, v29, %[A3]\n\t" \
  "v_max_f32 v29, v29, %[A4]\n\t" \
  "s_nop 1\n\t" \
  "v_max_f32_dpp v29, v29, v29 row_ror:8 row_mask:0xf bank_mask:0xf\n\t" \
  "s_nop 1\n\t" \
  "v_max_f32_dpp v29, v29, v29 row_ror:4 row_mask:0xf bank_mask:0xf\n\t" \
  "s_nop 1\n\t" \
  "v_max_f32_dpp v29, v29, v29 row_ror:2 row_mask:0xf bank_mask:0xf\n\t" \
  "s_nop 1\n\t" \
  "v_max_f32_dpp v29, v29, v29 row_ror:1 row_mask:0xf bank_mask:0xf\n\t" \
  "s_nop 1\n\t" \
  "v_readlane_b32 s91, v29, 0\n\t" \
  "v_readlane_b32 s92, v29, 16\n\t" \
  "v_readlane_b32 s93, v29, 32\n\t" \
  "v_readlane_b32 s94, v29, 48\n\t" \
  "s_nop 1\n\t" \
  "s_max_u32 s91, s91, s92\n\t" \
  "s_max_u32 s93, s93, s94\n\t" \
  "s_max_u32 s91, s91, s93\n\t" \
  "s_lshr_b32 s92, s91, 23\n\t" \
  "s_and_b32 s92, s92, 0xff\n\t" \
  "s_sub_u32 s93, 0x126, s92\n\t" \
  "s_min_u32 s93, s93, 0xfe\n\t" \
  "s_lshl_b32 s94, s93, 23\n\t" \
  "s_sub_u32 s95, 0x7f, s93\n\t" \
  "s_add_u32 %[EA], %[EA], s95\n\t" \
  "v_mul_f32 %[A0], s94, %[A0]\n\t" \
  "v_mul_f32 %[A1], s94, %[A1]\n\t" \
  "v_mul_f32 %[A2], s94, %[A2]\n\t" \
  "v_mul_f32 %[A3], s94, %[A3]\n\t" \
  "v_mul_f32 %[A4], s94, %[A4]\n\t"

#define STEP(Q1,Q3,QB) \
  "s_waitcnt vmcnt(45)\n\t" COMMIT(Q1,Q3,QB) ROWLOAD(Q1,Q3,QB) ALPHA
#define STEPR(Q1,Q3,QB)  STEP(Q1,Q3,QB) RENORM
#define ESTEP(Q1,Q3,QB)  COMMIT(Q1,Q3,QB) ALPHA
#define ESTEPR(Q1,Q3,QB) ESTEP(Q1,Q3,QB) RENORM

__global__ __launch_bounds__(64) void ctc_alpha_kernel(
    const int*   __restrict__ y_true,   // (B, U) int32
    const float* __restrict__ y_pred,   // (B, T, C) f32 softmax probs
    float*       __restrict__ out,      // (B, 1) f32
    int B)
{
  const int b = blockIdx.x;
  if (b >= B) return;
  const int lane = threadIdx.x;           // 0..63
  const float* __restrict__ p  = y_pred + (size_t)b * (T_DIM * C_DIM);
  const int*   __restrict__ yb = y_true + b * U_DIM;
  const int blank = C_DIM - 1;

  // Labels for this lane's odd states: s=4l+1 -> u=2l ; s=4l+3 -> u=2l+1
  const int ylab0 = yb[2 * lane];
  const int ylab1 = yb[2 * lane + 1];
  int yprev = blank;
  if (lane > 0) yprev = yb[2 * lane - 1];
  const float allow1 = (lane > 0 && ylab0 != blank && ylab0 != yprev) ? 1.0f : 0.0f;
  const float allow3 = (ylab1 != blank && ylab1 != ylab0)             ? 1.0f : 0.0f;

  const int o1 = ylab0 * 4;            // byte offset of label0 within a row
  const int o3 = ylab1 * 4;            // byte offset of label1 within a row

  // Virtual init: alpha_{-1}=1 on lane0 makes t=0 a uniform step.
  float a0 = (lane == 0) ? 1.0f : 0.0f;
  float a1 = 0.f, a2 = 0.f, a3 = 0.f, a4 = 0.f;
  int   e_acc = 0;

  asm volatile(
    // ---- prologue: init address/constant regs, prefill 16 rows (48 loads)
    "v_mov_b32 v20, %[O1]\n\t"
    "v_mov_b32 v21, %[O3]\n\t"
    "v_mov_b32 v22, 0\n\t"
    "v_mov_b32 v30, %[L1]\n\t"
    "v_mov_b32 v31, %[L3]\n\t"
    ROWLOAD("v32","v48","v64") ROWLOAD("v33","v49","v65")
    ROWLOAD("v34","v50","v66") ROWLOAD("v35","v51","v67")
    ROWLOAD("v36","v52","v68") ROWLOAD("v37","v53","v69")
    ROWLOAD("v38","v54","v70") ROWLOAD("v39","v55","v71")
    ROWLOAD("v40","v56","v72") ROWLOAD("v41","v57","v73")
    ROWLOAD("v42","v58","v74") ROWLOAD("v43","v59","v75")
    ROWLOAD("v44","v60","v76") ROWLOAD("v45","v61","v77")
    ROWLOAD("v46","v62","v78") ROWLOAD("v47","v63","v79")
    // ---- main loop: 63 iterations x 16 steps = steps 0..1007
    "s_mov_b32 s90, 63\n"
    "Lmain_%=:\n\t"
    STEP ("v32","v48","v64")  // u=0  (ph 0)
    STEP ("v33","v49","v65")  // u=1
    STEP ("v34","v50","v66")  // u=2
    STEP ("v35","v51","v67")  // u=3
    STEP ("v36","v52","v68")  // u=4
    STEP ("v37","v53","v69")  // u=5
    STEP ("v38","v54","v70")  // u=6
    STEPR("v39","v55","v71")  // u=7  renorm
    STEP ("v40","v56","v72")  // u=8
    STEP ("v41","v57","v73")  // u=9
    STEP ("v42","v58","v74")  // u=10
    STEP ("v43","v59","v75")  // u=11
    STEP ("v44","v60","v76")  // u=12
    STEP ("v45","v61","v77")  // u=13
    STEP ("v46","v62","v78")  // u=14
    STEPR("v47","v63","v79")  // u=15 renorm
    "s_sub_u32 s90, s90, 1\n\t"
    "s_cmp_lg_u32 s90, 0\n\t"
    "s_cbranch_scc1 Lmain_%=\n\t"
    // ---- epilogue: steps 1008..1023; drain ALL loads first, no refills
    "s_waitcnt vmcnt(0)\n\t"
    ESTEP ("v32","v48","v64")
    ESTEP ("v33","v49","v65")
    ESTEP ("v34","v50","v66")
    ESTEP ("v35","v51","v67")
    ESTEP ("v36","v52","v68")
    ESTEP ("v37","v53","v69")
    ESTEP ("v38","v54","v70")
    ESTEPR("v39","v55","v71")
    ESTEP ("v40","v56","v72")
    ESTEP ("v41","v57","v73")
    ESTEP ("v42","v58","v74")
    ESTEP ("v43","v59","v75")
    ESTEP ("v44","v60","v76")
    ESTEP ("v45","v61","v77")
    ESTEP ("v46","v62","v78")
    ESTEP ("v47","v63","v79")
    : [A0]"+v"(a0), [A1]"+v"(a1), [A2]"+v"(a2), [A3]"+v"(a3), [A4]"+v"(a4),
      [EA]"+s"(e_acc)
    : [P]"s"(p), [O1]"v"(o1), [O3]"v"(o3), [L1]"v"(allow1), [L3]"v"(allow3)
    : "v20","v21","v22","v23","v24","v25","v26","v27","v28","v29","v30","v31",
      "v32","v33","v34","v35","v36","v37","v38","v39","v40","v41","v42","v43",
      "v44","v45","v46","v47","v48","v49","v50","v51","v52","v53","v54","v55",
      "v56","v57","v58","v59","v60","v61","v62","v63","v64","v65","v66","v67",
      "v68","v69","v70","v71","v72","v73","v74","v75","v76","v77","v78","v79",
      "s90","s91","s92","s93","s94","s95","scc","memory");

  if (lane == 63) {
    float s = a3 + a4;                 // alpha[255] + alpha[256]
    s = fmaxf(s, 1e-37f);
    float ll = logf(s) + (float)e_acc * LN2F;
    out[b] = -ll;
  }
}

extern "C" void kernel_launch(void* const* d_in, const int* in_sizes, int n_in,
                              void* d_out, int out_size, void* d_ws, size_t ws_size,
                              hipStream_t stream) {
  const int*   y_true = (const int*)d_in[0];
  const float* y_pred = (const float*)d_in[1];
  float*       out    = (float*)d_out;
  const int B = in_sizes[0] / U_DIM;   // 256
  ctc_alpha_kernel<<<dim3(B), dim3(64), 0, stream>>>(y_true, y_pred, out, B);
}

// Round 8
// 200.472 us; speedup vs baseline: 1.2768x; 1.0094x over previous
//
#include <hip/hip_runtime.h>
#include <math.h>

// CTC forward loss, linear-domain alpha recursion, power-of-2 renorm.
// B=256 -> one wave per batch/CU. Lane l owns states 4l..4l+3 (+ state 256
// as slot 4 on lane 63).
//
// Round-8: R7's scattered per-label gathers were the stall (address-divergent
// loads, L_eff ~2300cy, step = L/15 ~152cy). Restructure: HBM side is pure
// streaming (global_load_dwordx4 = 2 rows/instr into a 16-chunk VGPR ring,
// 30-step slack), rows are ds_write_b128'd into a 32-row LDS ring, and the
// per-label gather becomes 3 ds_read_b32 with CONSTANT lane addresses (ring
// position in the static offset: immediate). DS is in-order -> fixed
// lgkmcnt(4) waits, reads pipelined 2 rows ahead (A/B ping-pong v16-18/v19-21).
// All control in ONE asm volatile with hard-coded clobbered registers
// (v10-v95, s90-95) -- the allocator cannot touch the in-flight queues.
// Commit/alpha/renorm identical to R7 -> same numerics.

#define T_DIM 1024
#define C_DIM 128
#define U_DIM 128
#define LN2F  0.6931471805599453f

#define EPS_LIT "0x33d6bf95"   /* 1e-7f */

// ---- register map (inside the blob) --------------------------------------
// v10 global voffset (lane*16 + chunk byte offset, +0x400/chunk)
// v11 LDS write addr (lane*16)         v12/v13 LDS read addr label0/label1
// v14 LDS read addr blank base         v16-18 read bank A  v19-21 read bank B
// v23-25 alpha temps  v26=cb v27=c1 v28=c3  v29 renorm  v30=allow1 v31=allow3
// v32-95: 16-chunk global queue (chunk c -> v[32+4*(c&15)])
// s90 loop counter, s91-95 renorm scratch

#define RD(RC1,RC3,RCB,ROFF,RBOFF) \
  "ds_read_b32 " RC1 ", v12 offset:" ROFF "\n\t" \
  "ds_read_b32 " RC3 ", v13 offset:" ROFF "\n\t" \
  "ds_read_b32 " RCB ", v14 offset:" RBOFF "\n\t"

#define CMT(RC1,RC3,RCB) \
  "v_add_f32 v27, " EPS_LIT ", " RC1 "\n\t" \
  "v_add_f32 v28, " EPS_LIT ", " RC3 "\n\t" \
  "v_add_f32 v26, " EPS_LIT ", " RCB "\n\t"

#define ALPHA \
  "v_mov_b32_dpp v23, %[A3] wave_shr:1 row_mask:0xf bank_mask:0xf bound_ctrl:0\n\t" \
  "v_add_f32 v24, %[A0], v23\n\t" \
  "v_add_f32 v25, %[A0], %[A1]\n\t" \
  "v_fma_f32 v25, v23, v30, v25\n\t" \
  "v_mul_f32 %[A0], v24, v26\n\t" \
  "v_add_f32 v24, %[A1], %[A2]\n\t" \
  "v_add_f32 v23, %[A2], %[A3]\n\t" \
  "v_fma_f32 v23, %[A1], v31, v23\n\t" \
  "v_mul_f32 %[A1], v25, v27\n\t" \
  "v_mul_f32 %[A2], v24, v26\n\t" \
  "v_add_f32 v24, %[A3], %[A4]\n\t" \
  "v_mul_f32 %[A3], v23, v28\n\t" \
  "v_mul_f32 %[A4], v24, v26\n\t"

#define RENORM \
  "v_max_f32 v29, %[A0], %[A1]\n\t" \
  "v_max_f32 v29, v29, %[A2]\n\t" \
  "v_max_f32 v29, v29, %[A3]\n\t" \
  "v_max_f32 v29, v29, %[A4]\n\t" \
  "s_nop 1\n\t" \
  "v_max_f32_dpp v29, v29, v29 row_ror:8 row_mask:0xf bank_mask:0xf\n\t" \
  "s_nop 1\n\t" \
  "v_max_f32_dpp v29, v29, v29 row_ror:4 row_mask:0xf bank_mask:0xf\n\t" \
  "s_nop 1\n\t" \
  "v_max_f32_dpp v29, v29, v29 row_ror:2 row_mask:0xf bank_mask:0xf\n\t" \
  "s_nop 1\n\t" \
  "v_max_f32_dpp v29, v29, v29 row_ror:1 row_mask:0xf bank_mask:0xf\n\t" \
  "s_nop 1\n\t" \
  "v_readlane_b32 s91, v29, 0\n\t" \
  "v_readlane_b32 s92, v29, 16\n\t" \
  "v_readlane_b32 s93, v29, 32\n\t" \
  "v_readlane_b32 s94, v29, 48\n\t" \
  "s_nop 1\n\t" \
  "s_max_u32 s91, s91, s92\n\t" \
  "s_max_u32 s93, s93, s94\n\t" \
  "s_max_u32 s91, s91, s93\n\t" \
  "s_lshr_b32 s92, s91, 23\n\t" \
  "s_and_b32 s92, s92, 0xff\n\t" \
  "s_sub_u32 s93, 0x126, s92\n\t" \
  "s_min_u32 s93, s93, 0xfe\n\t" \
  "s_lshl_b32 s94, s93, 23\n\t" \
  "s_sub_u32 s95, 0x7f, s93\n\t" \
  "s_add_u32 %[EA], %[EA], s95\n\t" \
  "v_mul_f32 %[A0], s94, %[A0]\n\t" \
  "v_mul_f32 %[A1], s94, %[A1]\n\t" \
  "v_mul_f32 %[A2], s94, %[A2]\n\t" \
  "v_mul_f32 %[A3], s94, %[A3]\n\t" \
  "v_mul_f32 %[A4], s94, %[A4]\n\t"

// Even step (steady): wait chunk m+1, write it to LDS, load chunk m+16,
// commit row t from bank A, issue reads for row t+2 into bank A.
#define SE(QW,WOFF,QL,RBOFF) \
  "s_waitcnt vmcnt(14)\n\t" \
  "ds_write_b128 v11, v[" QW "] offset:" WOFF "\n\t" \
  "global_load_dwordx4 v[" QL "], v10, %[P]\n\t" \
  "v_add_u32 v10, 0x400, v10\n\t" \
  "s_waitcnt lgkmcnt(4)\n\t" \
  CMT("v16","v17","v18") \
  RD("v16","v17","v18", WOFF, RBOFF) \
  ALPHA

// Odd step: commit row t from bank B, issue reads for row t+2 into bank B.
#define SO(ROFF,RBOFF) \
  "s_waitcnt lgkmcnt(4)\n\t" \
  CMT("v19","v20","v21") \
  RD("v19","v20","v21", ROFF, RBOFF) \
  ALPHA

// Tail even step (no more global loads; descending vmcnt).
#define TE(VC,QW,WOFF,RBOFF) \
  "s_waitcnt vmcnt(" VC ")\n\t" \
  "ds_write_b128 v11, v[" QW "] offset:" WOFF "\n\t" \
  "s_waitcnt lgkmcnt(4)\n\t" \
  CMT("v16","v17","v18") \
  RD("v16","v17","v18", WOFF, RBOFF) \
  ALPHA

__global__ __launch_bounds__(64) void ctc_alpha_kernel(
    const int*   __restrict__ y_true,   // (B, U) int32
    const float* __restrict__ y_pred,   // (B, T, C) f32 softmax probs
    float*       __restrict__ out,      // (B, 1) f32
    int B)
{
  __shared__ float4 ldsbuf[1024];       // 16 KB: 32-row x 512 B ring

  const int b = blockIdx.x;
  if (b >= B) return;
  const int lane = threadIdx.x;           // 0..63
  const float* __restrict__ p  = y_pred + (size_t)b * (T_DIM * C_DIM);
  const int*   __restrict__ yb = y_true + b * U_DIM;
  const int blank = C_DIM - 1;

  // Labels for this lane's odd states: s=4l+1 -> u=2l ; s=4l+3 -> u=2l+1
  const int ylab0 = yb[2 * lane];
  const int ylab1 = yb[2 * lane + 1];
  int yprev = blank;
  if (lane > 0) yprev = yb[2 * lane - 1];
  const float allow1 = (lane > 0 && ylab0 != blank && ylab0 != yprev) ? 1.0f : 0.0f;
  const float allow3 = (ylab1 != blank && ylab1 != ylab0)             ? 1.0f : 0.0f;

  // LDS byte offset of the ring (single shared var -> 0; low 32 bits of the
  // generic address ARE the LDS offset since the aperture is 4GB-aligned).
  const unsigned lds_off = (unsigned)(uintptr_t)(void*)ldsbuf;
  const int gvoff = lane * 16;                    // global: lane slice of a 1KB chunk
  const int wraddr = (int)lds_off + lane * 16;    // LDS write addr
  const int rd1    = (int)lds_off + ylab0 * 4;    // LDS read addr, label0
  const int rd3    = (int)lds_off + ylab1 * 4;    // LDS read addr, label1
  const int rdb    = (int)lds_off;                // blank via offset imm +508

  // Virtual init: alpha_{-1}=1 on lane0 makes t=0 a uniform step.
  float a0 = (lane == 0) ? 1.0f : 0.0f;
  float a1 = 0.f, a2 = 0.f, a3 = 0.f, a4 = 0.f;
  int   e_acc = 0;

  asm volatile(
    // ---- prologue ------------------------------------------------------
    "s_mov_b32 m0, -1\n\t"
    "v_mov_b32 v10, %[GV]\n\t"
    "v_mov_b32 v11, %[WA]\n\t"
    "v_mov_b32 v12, %[R1]\n\t"
    "v_mov_b32 v13, %[R3]\n\t"
    "v_mov_b32 v14, %[RB]\n\t"
    "v_mov_b32 v30, %[L1]\n\t"
    "v_mov_b32 v31, %[L3]\n\t"
    // prefill 16 chunks (rows 0..31)
    "global_load_dwordx4 v[32:35], v10, %[P]\n\t" "v_add_u32 v10, 0x400, v10\n\t"
    "global_load_dwordx4 v[36:39], v10, %[P]\n\t" "v_add_u32 v10, 0x400, v10\n\t"
    "global_load_dwordx4 v[40:43], v10, %[P]\n\t" "v_add_u32 v10, 0x400, v10\n\t"
    "global_load_dwordx4 v[44:47], v10, %[P]\n\t" "v_add_u32 v10, 0x400, v10\n\t"
    "global_load_dwordx4 v[48:51], v10, %[P]\n\t" "v_add_u32 v10, 0x400, v10\n\t"
    "global_load_dwordx4 v[52:55], v10, %[P]\n\t" "v_add_u32 v10, 0x400, v10\n\t"
    "global_load_dwordx4 v[56:59], v10, %[P]\n\t" "v_add_u32 v10, 0x400, v10\n\t"
    "global_load_dwordx4 v[60:63], v10, %[P]\n\t" "v_add_u32 v10, 0x400, v10\n\t"
    "global_load_dwordx4 v[64:67], v10, %[P]\n\t" "v_add_u32 v10, 0x400, v10\n\t"
    "global_load_dwordx4 v[68:71], v10, %[P]\n\t" "v_add_u32 v10, 0x400, v10\n\t"
    "global_load_dwordx4 v[72:75], v10, %[P]\n\t" "v_add_u32 v10, 0x400, v10\n\t"
    "global_load_dwordx4 v[76:79], v10, %[P]\n\t" "v_add_u32 v10, 0x400, v10\n\t"
    "global_load_dwordx4 v[80:83], v10, %[P]\n\t" "v_add_u32 v10, 0x400, v10\n\t"
    "global_load_dwordx4 v[84:87], v10, %[P]\n\t" "v_add_u32 v10, 0x400, v10\n\t"
    "global_load_dwordx4 v[88:91], v10, %[P]\n\t" "v_add_u32 v10, 0x400, v10\n\t"
    "global_load_dwordx4 v[92:95], v10, %[P]\n\t" "v_add_u32 v10, 0x400, v10\n\t"
    // chunk 0 -> LDS slot 0; prime reads for rows 0 (bank A) and 1 (bank B)
    "s_waitcnt vmcnt(15)\n\t"
    "ds_write_b128 v11, v[32:35] offset:0\n\t"
    RD("v16","v17","v18", "0",   "508")
    RD("v19","v20","v21", "512", "1020")
    // ---- main loop: 31 superblocks x 32 steps = steps 0..991 ----------
    "s_mov_b32 s90, 31\n"
    "LM_%=:\n\t"
    SE("36:39","1024","32:35","1532")   SO("1536","2044")
    SE("40:43","2048","36:39","2556")   SO("2560","3068")
    SE("44:47","3072","40:43","3580")   SO("3584","4092")
    SE("48:51","4096","44:47","4604")   SO("4608","5116")   RENORM
    SE("52:55","5120","48:51","5628")   SO("5632","6140")
    SE("56:59","6144","52:55","6652")   SO("6656","7164")
    SE("60:63","7168","56:59","7676")   SO("7680","8188")
    SE("64:67","8192","60:63","8700")   SO("8704","9212")   RENORM
    SE("68:71","9216","64:67","9724")   SO("9728","10236")
    SE("72:75","10240","68:71","10748") SO("10752","11260")
    SE("76:79","11264","72:75","11772") SO("11776","12284")
    SE("80:83","12288","76:79","12796") SO("12800","13308") RENORM
    SE("84:87","13312","80:83","13820") SO("13824","14332")
    SE("88:91","14336","84:87","14844") SO("14848","15356")
    SE("92:95","15360","88:91","15868") SO("15872","16380")
    SE("32:35","0","92:95","508")       SO("512","1020")    RENORM
    "s_sub_u32 s90, s90, 1\n\t"
    "s_cmp_lg_u32 s90, 0\n\t"
    "s_cbranch_scc1 LM_%=\n\t"
    // ---- tail: steps 992..1023 (no more global loads) ------------------
    TE("14","36:39","1024","1532")   SO("1536","2044")
    TE("13","40:43","2048","2556")   SO("2560","3068")
    TE("12","44:47","3072","3580")   SO("3584","4092")
    TE("11","48:51","4096","4604")   SO("4608","5116")   RENORM
    TE("10","52:55","5120","5628")   SO("5632","6140")
    TE("9","56:59","6144","6652")    SO("6656","7164")
    TE("8","60:63","7168","7676")    SO("7680","8188")
    TE("7","64:67","8192","8700")    SO("8704","9212")   RENORM
    TE("6","68:71","9216","9724")    SO("9728","10236")
    TE("5","72:75","10240","10748")  SO("10752","11260")
    TE("4","76:79","11264","11772")  SO("11776","12284")
    TE("3","80:83","12288","12796")  SO("12800","13308") RENORM
    TE("2","84:87","13312","13820")  SO("13824","14332")
    TE("1","88:91","14336","14844")  SO("14848","15356")
    TE("0","92:95","15360","15868")  SO("15872","16380")
    // k=15: steps 1022/1023 -- no writes, no further reads
    "s_waitcnt lgkmcnt(3)\n\t"
    CMT("v16","v17","v18")
    ALPHA
    "s_waitcnt lgkmcnt(0)\n\t"
    CMT("v19","v20","v21")
    ALPHA
    RENORM
    : [A0]"+v"(a0), [A1]"+v"(a1), [A2]"+v"(a2), [A3]"+v"(a3), [A4]"+v"(a4),
      [EA]"+s"(e_acc)
    : [P]"s"(p), [GV]"v"(gvoff), [WA]"v"(wraddr), [R1]"v"(rd1), [R3]"v"(rd3),
      [RB]"v"(rdb), [L1]"v"(allow1), [L3]"v"(allow3)
    : "v10","v11","v12","v13","v14","v15","v16","v17","v18","v19","v20","v21",
      "v22","v23","v24","v25","v26","v27","v28","v29","v30","v31",
      "v32","v33","v34","v35","v36","v37","v38","v39","v40","v41","v42","v43",
      "v44","v45","v46","v47","v48","v49","v50","v51","v52","v53","v54","v55",
      "v56","v57","v58","v59","v60","v61","v62","v63","v64","v65","v66","v67",
      "v68","v69","v70","v71","v72","v73","v74","v75","v76","v77","v78","v79",
      "v80","v81","v82","v83","v84","v85","v86","v87","v88","v89","v90","v91",
      "v92","v93","v94","v95",
      "s90","s91","s92","s93","s94","s95","scc","memory");

  if (lane == 63) {
    float s = a3 + a4;                 // alpha[255] + alpha[256]
    s = fmaxf(s, 1e-37f);
    float ll = logf(s) + (float)e_acc * LN2F;
    out[b] = -ll;
  }
}

extern "C" void kernel_launch(void* const* d_in, const int* in_sizes, int n_in,
                              void* d_out, int out_size, void* d_ws, size_t ws_size,
                              hipStream_t stream) {
  const int*   y_true = (const int*)d_in[0];
  const float* y_pred = (const float*)d_in[1];
  float*       out    = (float*)d_out;
  const int B = in_sizes[0] / U_DIM;   // 256
  ctc_alpha_kernel<<<dim3(B), dim3(64), 0, stream>>>(y_true, y_pred, out, B);
}